// Round 6
// baseline (349.913 us; speedup 1.0000x reference)
//
#include <hip/hip_runtime.h>
#include <hip/hip_bf16.h>

typedef unsigned short u16;
typedef __attribute__((ext_vector_type(8))) short short8;
typedef __attribute__((ext_vector_type(4))) float f32x4;

__device__ __forceinline__ float bf2f(u16 u){
  union { unsigned int i; float f; } c; c.i = ((unsigned int)u) << 16; return c.f;
}
__device__ __forceinline__ float lo2f(unsigned u){
  union { unsigned int i; float f; } c; c.i = u << 16; return c.f;
}
__device__ __forceinline__ float hi2f(unsigned u){
  union { unsigned int i; float f; } c; c.i = u & 0xffff0000u; return c.f;
}
__device__ __forceinline__ u16 f2bf(float f){
  union { float f; unsigned int i; } c; c.f = f;
  unsigned int x = c.i;
  return (u16)((x + 0x7FFFu + ((x >> 16) & 1u)) >> 16);  // RNE
}

// int64-aware edge fetch (values < 2^31, little-endian: low word is the value)
__device__ __forceinline__ int edge_get(const int* __restrict__ e32, int i64, int e, int c){
  int idx = 2 * e + c;
  return i64 ? e32[2 * idx] : e32[idx];
}

// ---------------------------------------------------------------------------
// Dtype detection (R1/R2 evidence: inputs ARE fp32; kept as insurance).
// flags[0]=1 -> float inputs fp32 (else bf16); flags[1]=1 -> edges int64.
// ---------------------------------------------------------------------------
__global__ void detect_kernel(const u16* __restrict__ lig16,
                              const int* __restrict__ e32, int* __restrict__ flags)
{
  int lane = threadIdx.x;
  int cnt = 0, nz = 0;
  #pragma unroll
  for (int j = 0; j < 4; j++){
    u16 u = lig16[(lane * 4 + j) * 2];
    int ex = (u >> 7) & 0xFF;
    if (ex >= 96 && ex < 160) cnt++;
    if (e32[(lane * 4 + j) * 2 + 1] != 0) nz++;
  }
  #pragma unroll
  for (int off = 1; off < 64; off <<= 1){
    cnt += __shfl_xor(cnt, off);
    nz  += __shfl_xor(nz, off);
  }
  if (lane == 0){
    flags[0] = (cnt < 128) ? 1 : 0;
    flags[1] = (nz == 0) ? 1 : 0;
  }
}

// ---------------------------------------------------------------------------
// prep_w: Wt[mat][n][k] = bf16(W[mat][k][n]) for Wq,Wk,Wv,Wo; biases -> fp32.
// ---------------------------------------------------------------------------
__global__ __launch_bounds__(256) void prep_w(
    const void* __restrict__ Wq, const void* __restrict__ Wk,
    const void* __restrict__ Wv, const void* __restrict__ Wo,
    const void* __restrict__ bq, const void* __restrict__ bk,
    const void* __restrict__ bv, const void* __restrict__ bo,
    u16* __restrict__ Wt, float* __restrict__ biasP, const int* __restrict__ flags)
{
  int mat = blockIdx.x, tid = threadIdx.x;
  const void* W = (mat == 0) ? Wq : (mat == 1) ? Wk : (mat == 2) ? Wv : Wo;
  const void* b = (mat == 0) ? bq : (mat == 1) ? bk : (mat == 2) ? bv : bo;
  int F = flags[0];
  u16* dst = Wt + mat * 16384;
  #pragma unroll 4
  for (int j = 0; j < 64; j++){
    int idx = tid + j * 256;            // k = idx>>7, n = idx&127
    u16 w = F ? f2bf(((const float*)W)[idx]) : ((const u16*)W)[idx];
    dst[(idx & 127) * 128 + (idx >> 7)] = w;
  }
  if (tid < 128)
    biasP[mat * 128 + tid] = F ? ((const float*)b)[tid] : bf2f(((const u16*)b)[tid]);
}

// ---------------------------------------------------------------------------
// gemm_multi: two input regions x nm weight mats, MFMA 16x16x32 bf16,
// 64x128 tile, LDS-staged coalesced epilogue. Per-mat output base + row
// stride (elements) so K/V can be written interleaved (KV[n][0:128]=K,
// [128:256]=V) for the attention gather.
// ---------------------------------------------------------------------------
__global__ __launch_bounds__(256) void gemm_multi(
    const void* __restrict__ A0, int M0, const void* __restrict__ A1, int M1, int mb0,
    const u16* __restrict__ Wt, const float* __restrict__ biasP, int wbase, int nm,
    u16* __restrict__ O0b, u16* __restrict__ O1b, u16* __restrict__ O2b,
    int s0, int s1, int s2,
    float* __restrict__ O0f,
    int a_force_bf16, int final_out, const int* __restrict__ flags)
{
  __shared__ __align__(16) char smem[52224];
  u16 (*As)[136]  = (u16(*)[136])smem;              // 64*136*2  = 17408 B
  u16 (*Ws)[136]  = (u16(*)[136])(smem + 17408);    // 128*136*2 = 34816 B
  float (*Fs)[132] = (float(*)[132])(smem + 17408); // reuse: 64*132*4 = 33792 B

  int tid = threadIdx.x;
  int F = flags[0];
  int AF = a_force_bf16 ? 0 : F;       // A dtype: 1=fp32, 0=bf16
  int xb = blockIdx.x;
  const void* A; int M, m0, orow;
  if (xb < mb0){ A = A0; M = M0; m0 = xb * 64;          orow = m0; }
  else         { A = A1; M = M1; m0 = (xb - mb0) * 64;  orow = M0 + m0; }

  // Stage A tile (64 x 128)
  if (AF){
    const float* Af = (const float*)A;
    #pragma unroll
    for (int j = 0; j < 8; j++){
      int idx = tid + j * 256;
      int m = idx >> 5, k4 = idx & 31;
      float4 v = make_float4(0.f, 0.f, 0.f, 0.f);
      if (m0 + m < M) v = *(const float4*)&Af[(size_t)(m0 + m) * 128 + k4 * 4];
      ushort4 o; o.x = f2bf(v.x); o.y = f2bf(v.y); o.z = f2bf(v.z); o.w = f2bf(v.w);
      *(ushort4*)&As[m][k4 * 4] = o;
    }
  } else {
    const u16* Au = (const u16*)A;
    #pragma unroll
    for (int j = 0; j < 8; j++){
      int idx = tid + j * 256;
      int m = idx >> 5, k4 = idx & 31;
      ushort4 v = make_ushort4(0, 0, 0, 0);
      if (m0 + m < M) v = *(const ushort4*)&Au[(size_t)(m0 + m) * 128 + k4 * 4];
      *(ushort4*)&As[m][k4 * 4] = v;
    }
  }
  // Stage Wt[wbase]
  {
    const u16* Wsrc = Wt + (size_t)wbase * 16384;
    #pragma unroll
    for (int j = 0; j < 8; j++){
      int idx = tid + j * 256;
      *(short8*)&Ws[idx >> 4][(idx & 15) * 8] = *(const short8*)&Wsrc[idx * 8];
    }
  }
  __syncthreads();

  int wave = tid >> 6, lane = tid & 63;
  int quad = lane >> 4, ml = lane & 15;

  short8 af[4];
  #pragma unroll
  for (int kk = 0; kk < 4; kk++)
    af[kk] = *(const short8*)&As[wave * 16 + ml][kk * 32 + quad * 8];

  int f32out = final_out && F;

  for (int mat = 0; mat < nm; mat++){
    f32x4 acc[8];
    #pragma unroll
    for (int nt = 0; nt < 8; nt++) acc[nt] = (f32x4){0.f, 0.f, 0.f, 0.f};

    #pragma unroll
    for (int nt = 0; nt < 8; nt++){
      #pragma unroll
      for (int kk = 0; kk < 4; kk++){
        short8 bfr = *(const short8*)&Ws[nt * 16 + ml][kk * 32 + quad * 8];
        acc[nt] = __builtin_amdgcn_mfma_f32_16x16x32_bf16(af[kk], bfr, acc[nt], 0, 0, 0);
      }
    }

    __syncthreads();                    // everyone done reading Ws
    const float* bp = biasP + (size_t)(wbase + mat) * 128;
    #pragma unroll
    for (int nt = 0; nt < 8; nt++){
      float bcol = bp[nt * 16 + ml];
      #pragma unroll
      for (int r = 0; r < 4; r++)
        Fs[wave * 16 + quad * 4 + r][nt * 16 + ml] = acc[nt][r] + bcol;
    }
    __syncthreads();

    if (f32out){
      #pragma unroll
      for (int j = 0; j < 8; j++){
        int u = tid + j * 256;
        int row = u >> 5, c4 = (u & 31) * 4;
        if (m0 + row < M)
          *(float4*)&O0f[(size_t)(orow + row) * 128 + c4] = *(const float4*)&Fs[row][c4];
      }
    } else {
      u16* Cb    = (mat == 0) ? O0b : ((mat == 1) ? O1b : O2b);
      int stride = (mat == 0) ? s0  : ((mat == 1) ? s1  : s2);
      #pragma unroll
      for (int j = 0; j < 4; j++){
        int u = tid + j * 256;
        int row = u >> 4, c8 = (u & 15) * 8;
        if (m0 + row < M){
          float4 x = *(const float4*)&Fs[row][c8];
          float4 y = *(const float4*)&Fs[row][c8 + 4];
          short8 t8;
          t8[0] = (short)f2bf(x.x); t8[1] = (short)f2bf(x.y);
          t8[2] = (short)f2bf(x.z); t8[3] = (short)f2bf(x.w);
          t8[4] = (short)f2bf(y.x); t8[5] = (short)f2bf(y.y);
          t8[6] = (short)f2bf(y.z); t8[7] = (short)f2bf(y.w);
          *(short8*)&Cb[(size_t)(orow + row) * stride + c8] = t8;
        }
      }
    }

    if (mat + 1 < nm){
      __syncthreads();                  // done reading Fs (aliases Ws)
      const u16* Wsrc = Wt + (size_t)(wbase + mat + 1) * 16384;
      #pragma unroll
      for (int j = 0; j < 8; j++){
        int idx = tid + j * 256;
        *(short8*)&Ws[idx >> 4][(idx & 15) * 8] = *(const short8*)&Wsrc[idx * 8];
      }
      __syncthreads();
    }
  }
}

// ---------------------------------------------------------------------------
// edge_pre: fused RBF bias (ebias[E,8] = attr@Wr + br) + degree count.
// ---------------------------------------------------------------------------
__global__ __launch_bounds__(256) void edge_pre(
    const void* __restrict__ attr, const void* __restrict__ Wr,
    const void* __restrict__ br, float* __restrict__ ebias,
    const int* __restrict__ edges, const int* __restrict__ ls_p,
    const int* __restrict__ ps_p, int* __restrict__ cnt, int nlig, int E_,
    const int* __restrict__ flags)
{
  __shared__ float w[16][8];
  __shared__ float b[8];
  int tid = threadIdx.x;
  int F = flags[0];
  if (tid < 128) w[tid >> 3][tid & 7] = F ? ((const float*)Wr)[tid] : bf2f(((const u16*)Wr)[tid]);
  if (tid < 8)   b[tid] = F ? ((const float*)br)[tid] : bf2f(((const u16*)br)[tid]);
  __syncthreads();
  int e = blockIdx.x * 256 + tid;
  if (e >= E_) return;

  int I64 = flags[1];
  int dl = edge_get(edges, I64, e, 0) - ls_p[0];
  int dp = edge_get(edges, I64, e, 1) - ps_p[0];
  atomicAdd(&cnt[dl], 1);
  atomicAdd(&cnt[nlig + dp], 1);

  float a[16];
  if (F){
    const float* af = (const float*)attr;
    #pragma unroll
    for (int j = 0; j < 4; j++){
      float4 t = *(const float4*)&af[e * 16 + j * 4];
      a[4*j] = t.x; a[4*j+1] = t.y; a[4*j+2] = t.z; a[4*j+3] = t.w;
    }
  } else {
    const u16* au = (const u16*)attr;
    #pragma unroll
    for (int j = 0; j < 4; j++){
      ushort4 t = *(const ushort4*)&au[e * 16 + j * 4];
      a[4*j] = bf2f(t.x); a[4*j+1] = bf2f(t.y); a[4*j+2] = bf2f(t.z); a[4*j+3] = bf2f(t.w);
    }
  }
  #pragma unroll
  for (int hh = 0; hh < 8; hh++){
    float s = b[hh];
    #pragma unroll
    for (int r = 0; r < 16; r++) s += a[r] * w[r][hh];
    ebias[e * 8 + hh] = s;
  }
}

// ---------------------------------------------------------------------------
// scan_one: single-dispatch exclusive scan via parallel lookback.
// Each block scans its 256 chunk, publishes its aggregate with a release
// flag, then parallel-sums all prior aggregates (all blocks co-resident:
// n<=131072 -> <=512 blocks << capacity).
// ---------------------------------------------------------------------------
__global__ __launch_bounds__(256) void scan_one(
    const int* __restrict__ cnt, int* __restrict__ offs, int* __restrict__ cursor,
    int n, int* __restrict__ partial, int* __restrict__ flag)
{
  __shared__ int buf[256];
  int b = blockIdx.x, tid = threadIdx.x;
  int i = b * 256 + tid;
  int v = (i < n) ? cnt[i] : 0;
  buf[tid] = v; __syncthreads();
  #pragma unroll
  for (int off = 1; off < 256; off <<= 1){
    int t = (tid >= off) ? buf[tid - off] : 0;
    __syncthreads();
    buf[tid] += t;
    __syncthreads();
  }
  int myincl = buf[tid];
  if (tid == 0){
    partial[b] = buf[255];
    __hip_atomic_store(&flag[b], 1, __ATOMIC_RELEASE, __HIP_MEMORY_SCOPE_AGENT);
  }
  // parallel lookback: sum aggregates of blocks < b
  int acc = 0;
  for (int j = tid; j < b; j += 256){
    while (__hip_atomic_load(&flag[j], __ATOMIC_ACQUIRE, __HIP_MEMORY_SCOPE_AGENT) == 0){
      __builtin_amdgcn_s_sleep(1);
    }
    acc += partial[j];
  }
  __syncthreads();           // everyone done with buf (scan values saved)
  buf[tid] = acc; __syncthreads();
  #pragma unroll
  for (int off = 128; off > 0; off >>= 1){
    if (tid < off) buf[tid] += buf[tid + off];
    __syncthreads();
  }
  int prev = buf[0];
  int excl = myincl - v + prev;
  if (i < n){
    offs[i] = excl;
    cursor[i] = excl;
    if (i == n - 1) offs[n] = excl + v;
  }
}

__global__ __launch_bounds__(256) void scatter_kernel(
    const int* __restrict__ edges, const int* __restrict__ ls_p,
    const int* __restrict__ ps_p, int* __restrict__ cursor,
    int2* __restrict__ sorted, int nlig, int E_,
    const int* __restrict__ flags)
{
  int e = blockIdx.x * 256 + threadIdx.x;
  if (e >= E_) return;
  int I64 = flags[1];
  int dl = edge_get(edges, I64, e, 0) - ls_p[0];
  int dp = edge_get(edges, I64, e, 1) - ps_p[0];
  int p1 = atomicAdd(&cursor[dl], 1);        sorted[p1] = make_int2(e, nlig + dp);
  int p2 = atomicAdd(&cursor[nlig + dp], 1); sorted[p2] = make_int2(e, dl);
}

// ---------------------------------------------------------------------------
// Attention: one wave per destination node, online softmax, 2-edge unroll.
// KV interleaved (K at node*256, V at +128) -> one scalar base per edge,
// V load = K address + offset:256. Wave-uniform values forced to SGPRs via
// readfirstlane so gathers are [sgpr base + lane offset] with no VGPR
// address math (R5: 93 VALU instrs/edge-visit, VALUBusy 65%).
// ---------------------------------------------------------------------------
__global__ __launch_bounds__(256) void attn_kernel(
    const u16* __restrict__ Q, const u16* __restrict__ KV,
    const int2* __restrict__ sorted, const int* __restrict__ offs,
    const float* __restrict__ ebias, u16* __restrict__ AGG, int ntot)
{
  int t = blockIdx.x * 4 + (threadIdx.x >> 6);
  if (t >= ntot) return;
  int lane = threadIdx.x & 63, h = lane >> 3;

  ushort2 qu = *(const ushort2*)&Q[(size_t)t * 128 + lane * 2];
  float q0 = bf2f(qu.x), q1 = bf2f(qu.y);

  int ts = __builtin_amdgcn_readfirstlane(t);
  int beg = offs[ts], end = offs[ts + 1];
  float m = -INFINITY, l = 0.f, a0 = 0.f, a1 = 0.f;

  int i = beg;
  for (; i + 1 < end; i += 2){
    int2 c0 = sorted[i];
    int2 c1 = sorted[i + 1];
    int s0 = __builtin_amdgcn_readfirstlane(c0.y);
    int s1 = __builtin_amdgcn_readfirstlane(c1.y);
    int e0 = __builtin_amdgcn_readfirstlane(c0.x);
    int e1 = __builtin_amdgcn_readfirstlane(c1.x);
    const u16* r0 = KV + (size_t)s0 * 256 + lane * 2;
    const u16* r1 = KV + (size_t)s1 * 256 + lane * 2;
    unsigned k0p = *(const unsigned*)r0;
    unsigned v0p = *(const unsigned*)(r0 + 128);
    unsigned k1p = *(const unsigned*)r1;
    unsigned v1p = *(const unsigned*)(r1 + 128);
    float eb0 = ebias[(size_t)e0 * 8 + h];
    float eb1 = ebias[(size_t)e1 * 8 + h];

    float d0 = fmaf(q0, lo2f(k0p), q1 * hi2f(k0p));
    d0 += __shfl_xor(d0, 1); d0 += __shfl_xor(d0, 2); d0 += __shfl_xor(d0, 4);
    float d1 = fmaf(q0, lo2f(k1p), q1 * hi2f(k1p));
    d1 += __shfl_xor(d1, 1); d1 += __shfl_xor(d1, 2); d1 += __shfl_xor(d1, 4);

    float l0 = fmaf(d0, 0.25f, eb0);       // SCALE = 16^-0.5
    float l1 = fmaf(d1, 0.25f, eb1);
    float nm = fmaxf(m, fmaxf(l0, l1));
    float alpha = __expf(m - nm);          // exp(-inf)=0 first time
    float p0 = __expf(l0 - nm);
    float p1 = __expf(l1 - nm);
    a0 = fmaf(a0, alpha, fmaf(p0, lo2f(v0p), p1 * lo2f(v1p)));
    a1 = fmaf(a1, alpha, fmaf(p0, hi2f(v0p), p1 * hi2f(v1p)));
    l  = fmaf(l,  alpha, p0 + p1);
    m = nm;
  }
  if (i < end){                            // tail edge
    int2 c = sorted[i];
    int s0 = __builtin_amdgcn_readfirstlane(c.y);
    int e0 = __builtin_amdgcn_readfirstlane(c.x);
    const u16* r0 = KV + (size_t)s0 * 256 + lane * 2;
    unsigned k0p = *(const unsigned*)r0;
    unsigned v0p = *(const unsigned*)(r0 + 128);
    float eb0 = ebias[(size_t)e0 * 8 + h];
    float d0 = fmaf(q0, lo2f(k0p), q1 * hi2f(k0p));
    d0 += __shfl_xor(d0, 1); d0 += __shfl_xor(d0, 2); d0 += __shfl_xor(d0, 4);
    float l0 = fmaf(d0, 0.25f, eb0);
    float nm = fmaxf(m, l0);
    float alpha = __expf(m - nm);
    float p0 = __expf(l0 - nm);
    a0 = fmaf(a0, alpha, p0 * lo2f(v0p));
    a1 = fmaf(a1, alpha, p0 * hi2f(v0p));
    l  = fmaf(l,  alpha, p0);
    m = nm;
  }
  float inv = 1.f / (l + 1e-8f);           // empty segment -> 0, matches ref
  ushort2 o; o.x = f2bf(a0 * inv); o.y = f2bf(a1 * inv);
  *(ushort2*)&AGG[(size_t)t * 128 + lane * 2] = o;
}

// ---------------------------------------------------------------------------
extern "C" void kernel_launch(void* const* d_in, const int* in_sizes, int n_in,
                              void* d_out, int out_size, void* d_ws, size_t ws_size,
                              hipStream_t stream)
{
  const void* ligand_x  = d_in[0];
  const void* protein_x = d_in[1];
  const int* edges      = (const int*)d_in[2];
  const void* attr      = d_in[3];
  const void* Wq = d_in[4];  const void* bq = d_in[5];
  const void* Wk = d_in[6];  const void* bk = d_in[7];
  const void* Wv = d_in[8];  const void* bv = d_in[9];
  const void* Wo = d_in[10]; const void* bo = d_in[11];
  const void* Wr = d_in[12]; const void* br = d_in[13];
  const int* ls_p = (const int*)d_in[14];
  const int* ps_p = (const int*)d_in[15];

  const int nlig = in_sizes[0] / 128;
  const int nprot = in_sizes[1] / 128;
  const int E = in_sizes[2] / 2;
  const int ntot = nlig + nprot;

  char* w = (char*)d_ws;
  size_t off = 0;
  auto alloc = [&](size_t bytes) -> void* {
    void* p = w + off;
    off = (off + bytes + 255) & ~(size_t)255;
    return p;
  };
  int*   flags = (int*)alloc(256);
  u16*   Wt    = (u16*)alloc(4 * 16384 * 2);
  float* biasP = (float*)alloc(4 * 128 * 4);
  u16* Qb  = (u16*)alloc((size_t)ntot * 128 * 2);
  u16* KV  = (u16*)alloc((size_t)ntot * 256 * 2);   // K at node*256, V at +128
  u16* AGG = (u16*)alloc((size_t)ntot * 128 * 2);
  float* ebias = (float*)alloc((size_t)E * 8 * 4);
  int* cnt  = (int*)alloc((size_t)ntot * 4);
  int* flag = (int*)alloc(512 * 4);                  // adjacent to cnt: one memset
  size_t zero_len = (size_t)((char*)flag - (char*)cnt) + 512 * 4;
  int* offs    = (int*)alloc((size_t)(ntot + 1) * 4);
  int* cursor  = (int*)alloc((size_t)ntot * 4);
  int* partial = (int*)alloc(512 * 4);
  int2* sorted = (int2*)alloc((size_t)2 * E * 8);
  (void)ws_size; (void)n_in; (void)out_size;

  const int mb_l = (nlig + 63) / 64;
  const int mb_p = (nprot + 63) / 64;
  const int mb_t = (ntot + 63) / 64;
  const int eb = (E + 255) / 256;
  const int nb = (ntot + 255) / 256;

  // 0. zero cnt+flag, detect dtypes, prep weights
  hipMemsetAsync(cnt, 0, zero_len, stream);
  detect_kernel<<<1, 64, 0, stream>>>((const u16*)ligand_x, edges, flags);
  prep_w<<<4, 256, 0, stream>>>(Wq, Wk, Wv, Wo, bq, bk, bv, bo, Wt, biasP, flags);

  // 1. fused q/k/v projection -> Q + interleaved KV
  gemm_multi<<<mb_l + mb_p, 256, 0, stream>>>(
      ligand_x, nlig, protein_x, nprot, mb_l,
      Wt, biasP, /*wbase=*/0, /*nm=*/3,
      Qb, KV, KV + 128, /*s0=*/128, /*s1=*/256, /*s2=*/256,
      nullptr, /*a_force_bf16=*/0, /*final=*/0, flags);

  // 2. fused rbf bias + degree count
  edge_pre<<<eb, 256, 0, stream>>>(attr, Wr, br, ebias, edges, ls_p, ps_p,
                                   cnt, nlig, E, flags);

  // 3. single-dispatch scan + scatter
  scan_one<<<nb, 256, 0, stream>>>(cnt, offs, cursor, ntot, partial, flag);
  scatter_kernel<<<eb, 256, 0, stream>>>(edges, ls_p, ps_p, cursor, sorted, nlig, E, flags);

  // 4. attention (one wave per destination node, combined space)
  attn_kernel<<<(ntot + 3) / 4, 256, 0, stream>>>(Qb, KV, sorted, offs, ebias, AGG, ntot);

  // 5. output projection: AGG[ntot] @ Wo + bo -> d_out (fp32 per flags)
  gemm_multi<<<mb_t, 256, 0, stream>>>(
      AGG, ntot, nullptr, 0, mb_t,
      Wt, biasP, /*wbase=*/3, /*nm=*/1,
      (u16*)d_out, nullptr, nullptr, 128, 128, 128,
      (float*)d_out, /*a_force_bf16=*/1, /*final=*/1, flags);
}